// Round 12
// baseline (549.551 us; speedup 1.0000x reference)
//
#include <hip/hip_runtime.h>
#include <math.h>

typedef unsigned short ushort_t;
typedef short short8 __attribute__((ext_vector_type(8)));
typedef float f32x4 __attribute__((ext_vector_type(4)));

#define DMODEL 1024
#define NHEADS 16
#define DKH    64
#define BATCH  2
#define SEQ    2048
#define BT     (BATCH * SEQ)   // 4096
#define NBLK   768             // 3 blocks/CU x 256 CUs; provably all co-resident

__device__ __forceinline__ ushort_t f2bf(float f) {
    union { float f; unsigned u; } a; a.f = f;
    return (ushort_t)((a.u + 0x7FFFu + ((a.u >> 16) & 1u)) >> 16);
}

__device__ __forceinline__ void async_copy16(const ushort_t* g, ushort_t* l) {
    __builtin_amdgcn_global_load_lds(
        (__attribute__((address_space(1))) void*)g,
        (__attribute__((address_space(3))) void*)l, 16, 0, 0);
}

// Grid barrier: valid because all NBLK blocks are co-resident (LDS 48 KB ->
// exactly 3 blocks/CU, grid = 3*256; __launch_bounds__(256,3) caps VGPRs).
// Agent-scope atomics reach the coherent point (L3) -> safe across XCDs (G16).
__device__ __forceinline__ void grid_barrier(unsigned* cnt) {
    __syncthreads();
    if (threadIdx.x == 0) {
        __threadfence();   // release all prior global writes (device scope)
        __hip_atomic_fetch_add(cnt, 1u, __ATOMIC_ACQ_REL, __HIP_MEMORY_SCOPE_AGENT);
        while (__hip_atomic_load(cnt, __ATOMIC_ACQUIRE, __HIP_MEMORY_SCOPE_AGENT) < NBLK)
            __builtin_amdgcn_s_sleep(1);
    }
    __syncthreads();
}

union Shm {
    struct { ushort_t At[2 * 4096]; ushort_t Bt[2 * 4096]; } q;  // qkv 32 KB
    struct { ushort_t At[2 * 4096]; ushort_t Bt[2 * 8192]; } o;  // out 48 KB
    struct { ushort_t Kt[2][4096]; ushort_t Vt[2][4096]; } a;    // attn 32 KB
    ushort_t tile[64][72];                                       // prep 9 KB
};

__global__ __launch_bounds__(256, 3) void fused_kernel(
    const float* __restrict__ x,
    const float* __restrict__ Wq, const float* __restrict__ bq,
    const float* __restrict__ Wk, const float* __restrict__ bk,
    const float* __restrict__ Wv, const float* __restrict__ bv,
    const float* __restrict__ Wo, const float* __restrict__ bo,
    ushort_t* __restrict__ xb,
    ushort_t* __restrict__ WqT, ushort_t* __restrict__ WkT,
    ushort_t* __restrict__ WvT, ushort_t* __restrict__ WoT,
    ushort_t* __restrict__ Qb, ushort_t* __restrict__ Kb,
    ushort_t* __restrict__ VTb, ushort_t* __restrict__ AOb,
    float* __restrict__ out, unsigned* __restrict__ bar)
{
    __shared__ Shm sh;
    const int bx  = blockIdx.x;
    const int tid = threadIdx.x;
    const int w    = tid >> 6, lane = tid & 63;
    const int l15  = lane & 15, quad = lane >> 4;
    const f32x4 zero = {0.f, 0.f, 0.f, 0.f};

    // ================= PHASE 0: prep (x cast + weight transpose) ===========
    for (int j = bx; j < 3072; j += NBLK) {
        if (j < 2048) {
            size_t i = ((size_t)j * 256 + tid) * 8;
            float4 a = *(const float4*)(x + i);
            float4 b = *(const float4*)(x + i + 4);
            union { ushort_t u[8]; short8 v; } r;
            r.u[0] = f2bf(a.x); r.u[1] = f2bf(a.y); r.u[2] = f2bf(a.z); r.u[3] = f2bf(a.w);
            r.u[4] = f2bf(b.x); r.u[5] = f2bf(b.y); r.u[6] = f2bf(b.z); r.u[7] = f2bf(b.w);
            *(short8*)(xb + i) = r.v;
        } else {
            const int idx = j - 2048;
            const int z  = idx >> 8;
            const int n0 = ((idx >> 4) & 15) * 64;
            const int k0 = (idx & 15) * 64;
            const float* W = (z == 0) ? Wq : (z == 1) ? Wk : (z == 2) ? Wv : Wo;
            ushort_t*   WT = (z == 0) ? WqT : (z == 1) ? WkT : (z == 2) ? WvT : WoT;

            const int r  = tid >> 2;
            const int cb = (tid & 3) * 16;
#pragma unroll
            for (int u = 0; u < 4; ++u) {
                float4 v = *(const float4*)(W + (size_t)(k0 + r) * DMODEL + n0 + cb + u * 4);
                union { ushort_t u4[4]; unsigned long long ll; } p;
                p.u4[0] = f2bf(v.x); p.u4[1] = f2bf(v.y);
                p.u4[2] = f2bf(v.z); p.u4[3] = f2bf(v.w);
                *(unsigned long long*)&sh.tile[r][cb + u * 4] = p.ll;
            }
            __syncthreads();
            const int n  = tid >> 2;
            const int kb = (tid & 3) * 16;
#pragma unroll
            for (int half = 0; half < 2; ++half) {
                union { ushort_t u8[8]; short8 v; } p;
#pragma unroll
                for (int jj = 0; jj < 8; ++jj) p.u8[jj] = sh.tile[kb + half * 8 + jj][n];
                *(short8*)(WT + (size_t)(n0 + n) * DMODEL + k0 + kb + half * 8) = p.v;
            }
            __syncthreads();
        }
    }

    grid_barrier(&bar[0]);

    // ================= PHASE 1: QKV GEMM (768 jobs, 1/block) ===============
    // BM=BN=128, BK=32 dbuf, pair-line swizzle (R11-proven, 0 conflicts)
    {
        const int z   = bx >> 8;
        const int rem = bx & 255;
        const int m0  = (rem & 31) * 128, n0 = (rem >> 5) * 128;
        const ushort_t* WT = (z == 0) ? WqT : (z == 1) ? WkT : WvT;
        const float* bias  = (z == 0) ? bq : (z == 1) ? bk : bv;

        const int wm = w >> 1, wn = w & 1;
        const int s    = (lane & 7) ^ ((lane >> 3) & 7);
        const int rofs = ((lane >> 3) << 1) | (s >> 2);
        const int cofs = (s & 3) << 3;

        f32x4 acc[4][4];
#pragma unroll
        for (int i = 0; i < 4; ++i)
#pragma unroll
            for (int jj = 0; jj < 4; ++jj) acc[i][jj] = zero;

        const ushort_t* Asrc = xb + (size_t)m0 * DMODEL + cofs;
        const ushort_t* Bsrc = WT + (size_t)n0 * DMODEL + cofs;

#pragma unroll
        for (int c = 0; c < 2; ++c) {
            int ch = w * 2 + c;
            async_copy16(Asrc + (size_t)(ch * 16 + rofs) * DMODEL, sh.q.At + ch * 512);
            async_copy16(Bsrc + (size_t)(ch * 16 + rofs) * DMODEL, sh.q.Bt + ch * 512);
        }
        __syncthreads();

        for (int kt = 0; kt < DMODEL / 32; ++kt) {
            const int cur = (kt & 1) << 12;
            if (kt + 1 < DMODEL / 32) {
                const int nxt = cur ^ 4096;
                const int k0 = (kt + 1) * 32;
#pragma unroll
                for (int c = 0; c < 2; ++c) {
                    int ch = w * 2 + c;
                    async_copy16(Asrc + (size_t)(ch * 16 + rofs) * DMODEL + k0,
                                 sh.q.At + nxt + ch * 512);
                    async_copy16(Bsrc + (size_t)(ch * 16 + rofs) * DMODEL + k0,
                                 sh.q.Bt + nxt + ch * 512);
                }
            }
            short8 af[4], bf[4];
#pragma unroll
            for (int t = 0; t < 4; ++t) {
                int ra = wm * 64 + t * 16 + l15;
                int rb = wn * 64 + t * 16 + l15;
                af[t] = *(const short8*)(sh.q.At + cur + (ra >> 1) * 64 +
                         (((((ra & 1) << 2) | quad) ^ ((ra >> 1) & 7)) << 3));
                bf[t] = *(const short8*)(sh.q.Bt + cur + (rb >> 1) * 64 +
                         (((((rb & 1) << 2) | quad) ^ ((rb >> 1) & 7)) << 3));
            }
#pragma unroll
            for (int mt = 0; mt < 4; ++mt)
#pragma unroll
                for (int nt = 0; nt < 4; ++nt)
                    acc[mt][nt] = __builtin_amdgcn_mfma_f32_16x16x32_bf16(
                        af[mt], bf[nt], acc[mt][nt], 0, 0, 0);
            __syncthreads();
        }

        float bcol[4];
#pragma unroll
        for (int nt = 0; nt < 4; ++nt) bcol[nt] = bias[n0 + wn * 64 + nt * 16 + l15];

        if (z == 2) {
#pragma unroll
            for (int mt = 0; mt < 4; ++mt) {
                int row0 = m0 + wm * 64 + mt * 16 + quad * 4;
                int b = row0 >> 11, t = row0 & (SEQ - 1);
                int tb = t & ~63;
                int idxp = ((mt & 1) << 2) | (quad << 3) | ((mt >> 1) << 5);
#pragma unroll
                for (int nt = 0; nt < 4; ++nt) {
                    int col = n0 + wn * 64 + nt * 16 + l15;
                    int h = col >> 6, d = col & 63;
                    union { ushort_t u4[4]; unsigned long long ll; } pk;
#pragma unroll
                    for (int reg = 0; reg < 4; ++reg)
                        pk.u4[reg] = f2bf(acc[mt][nt][reg] + bcol[nt]);
                    *(unsigned long long*)(VTb +
                        ((size_t)(b * NHEADS + h) * DKH + d) * SEQ + tb + idxp) = pk.ll;
                }
            }
        } else {
            ushort_t* outp = (z == 0) ? Qb : Kb;
#pragma unroll
            for (int mt = 0; mt < 4; ++mt)
#pragma unroll
                for (int reg = 0; reg < 4; ++reg) {
                    int row = m0 + wm * 64 + mt * 16 + quad * 4 + reg;
                    int b = row >> 11, t = row & (SEQ - 1);
#pragma unroll
                    for (int nt = 0; nt < 4; ++nt) {
                        int col = n0 + wn * 64 + nt * 16 + l15;
                        int h = col >> 6, d = col & 63;
                        outp[((((size_t)b * NHEADS + h) * SEQ + t) << 6) + d] =
                            f2bf(acc[mt][nt][reg] + bcol[nt]);
                    }
                }
        }
    }

    grid_barrier(&bar[1]);

    // ================= PHASE 2: attention (512 jobs on blocks < 512) =======
    if (bx < 512) {
        const int bi = bx;
        const int bh = bi & 31;              // same-head blocks share bi%8 (XCD)
        const int b  = bh >> 4, h = bh & 15;
        const int qq = bi >> 5;

        const ushort_t* Kbase = Kb + (((size_t)bh * SEQ) << 6);
        const ushort_t* Vbase = VTb + (size_t)bh * DKH * SEQ;

        const int srow = lane >> 3;
        const int schx = (lane & 7) ^ srow;
        const int swz  = l15 & 7;
        const float cexp = 0.18033688011112042f;   // 0.125 * log2(e)

        union { ushort_t u8[8]; short8 v; } ones;
#pragma unroll
        for (int jj = 0; jj < 8; ++jj) ones.u8[jj] = 0x3F80;

        for (int job = 0; job < 2; ++job) {
            const int qt = job ? (31 - qq) : qq;
            const int q0 = qt * 64;
            const int nk = qt + 1;

            short8 qa[2];
#pragma unroll
            for (int ks = 0; ks < 2; ++ks)
                qa[ks] = *(const short8*)(
                    Qb + (((size_t)bh * SEQ + q0 + w * 16 + l15) << 6) + ks * 32 + quad * 8);

            f32x4 lacc = zero;
            f32x4 o[4];
#pragma unroll
            for (int dt = 0; dt < 4; ++dt) o[dt] = zero;

#pragma unroll
            for (int c = 0; c < 2; ++c) {
                int chunk = w * 2 + c;
                async_copy16(Kbase + (((size_t)(chunk * 8 + srow)) << 6) + schx * 8,
                             &sh.a.Kt[0][chunk * 512]);
                async_copy16(Vbase + (size_t)(chunk * 8 + srow) * SEQ + schx * 8,
                             &sh.a.Vt[0][chunk * 512]);
            }
            __syncthreads();

            for (int kt = 0; kt < nk; ++kt) {
                const int buf = kt & 1;
                if (kt + 1 < nk) {
                    const int kt0n = (kt + 1) * 64;
#pragma unroll
                    for (int c = 0; c < 2; ++c) {
                        int chunk = w * 2 + c;
                        async_copy16(Kbase + (((size_t)(kt0n + chunk * 8 + srow)) << 6) + schx * 8,
                                     &sh.a.Kt[buf ^ 1][chunk * 512]);
                        async_copy16(Vbase + (size_t)(chunk * 8 + srow) * SEQ + kt0n + schx * 8,
                                     &sh.a.Vt[buf ^ 1][chunk * 512]);
                    }
                }

                short8 kf[4][2], vf[2][4];
#pragma unroll
                for (int kt_i = 0; kt_i < 4; ++kt_i)
#pragma unroll
                    for (int ks = 0; ks < 2; ++ks)
                        kf[kt_i][ks] = *(const short8*)&sh.a.Kt[buf][(kt_i * 16 + l15) * 64 +
                                                        (((ks * 4 + quad) ^ swz) << 3)];
#pragma unroll
                for (int g = 0; g < 2; ++g)
#pragma unroll
                    for (int dt = 0; dt < 4; ++dt)
                        vf[g][dt] = *(const short8*)&sh.a.Vt[buf][(dt * 16 + l15) * 64 +
                                                     ((((g << 2) | quad) ^ swz) << 3)];

                f32x4 sc[4];
#pragma unroll
                for (int kt_i = 0; kt_i < 4; ++kt_i) sc[kt_i] = zero;
#pragma unroll
                for (int ks = 0; ks < 2; ++ks)
#pragma unroll
                    for (int kt_i = 0; kt_i < 4; ++kt_i)
                        sc[kt_i] = __builtin_amdgcn_mfma_f32_16x16x32_bf16(
                            kf[kt_i][ks], qa[ks], sc[kt_i], 0, 0, 0);

                const bool domask = (kt == qt);
                const int qabs = q0 + w * 16 + l15;
                unsigned pka[4], pkb[4];
#pragma unroll
                for (int kt_i = 0; kt_i < 4; ++kt_i) {
                    float p[4];
#pragma unroll
                    for (int r = 0; r < 4; ++r) {
                        float pv = exp2f(cexp * sc[kt_i][r]);
                        if (domask && (kt * 64 + kt_i * 16 + quad * 4 + r) > qabs) pv = 0.f;
                        p[r] = pv;
                    }
                    pka[kt_i] = __builtin_amdgcn_perm(
                        __float_as_uint(p[1]), __float_as_uint(p[0]), 0x07060302u);
                    pkb[kt_i] = __builtin_amdgcn_perm(
                        __float_as_uint(p[3]), __float_as_uint(p[2]), 0x07060302u);
                }

#pragma unroll
                for (int g = 0; g < 2; ++g) {
                    union { unsigned u[4]; short8 v; } pf;
                    pf.u[0] = pka[2 * g];
                    pf.u[1] = pkb[2 * g];
                    pf.u[2] = pka[2 * g + 1];
                    pf.u[3] = pkb[2 * g + 1];
                    lacc = __builtin_amdgcn_mfma_f32_16x16x32_bf16(
                        pf.v, ones.v, lacc, 0, 0, 0);
#pragma unroll
                    for (int dt = 0; dt < 4; ++dt)
                        o[dt] = __builtin_amdgcn_mfma_f32_16x16x32_bf16(
                            pf.v, vf[g][dt], o[dt], 0, 0, 0);
                }

                __syncthreads();
            }

#pragma unroll
            for (int r = 0; r < 4; ++r) {
                float inv = 1.0f / lacc[r];
                int t = q0 + w * 16 + quad * 4 + r;
#pragma unroll
                for (int dt = 0; dt < 4; ++dt)
                    AOb[((size_t)b * SEQ + t) * DMODEL + h * 64 + dt * 16 + l15] =
                        f2bf(o[dt][r] * inv);
            }
        }
    }

    grid_barrier(&bar[2]);

    // ================= PHASE 3: output projection (512 jobs) ===============
    // BM=64, BN=128, BK=64 dbuf, XOR swizzle (R10-proven)
    if (bx < 512) {
        const int m0 = (bx & 63) * 64, n0 = (bx >> 6) * 128;
        const int wm = w & 1, wn = w >> 1;
        const int srow = lane >> 3;
        const int scol = ((lane & 7) ^ srow) << 3;
        const int swz  = l15 & 7;

        f32x4 acc[2][4];
#pragma unroll
        for (int i = 0; i < 2; ++i)
#pragma unroll
            for (int jj = 0; jj < 4; ++jj) acc[i][jj] = zero;

#pragma unroll
        for (int c = 0; c < 2; ++c) {
            int ch = w * 2 + c;
            async_copy16(AOb + (size_t)(m0 + ch * 8 + srow) * DMODEL + scol,
                         sh.o.At + ch * 512);
        }
#pragma unroll
        for (int c = 0; c < 4; ++c) {
            int ch = w * 4 + c;
            async_copy16(WoT + (size_t)(n0 + ch * 8 + srow) * DMODEL + scol,
                         sh.o.Bt + ch * 512);
        }
        __syncthreads();

        for (int kt = 0; kt < DMODEL / 64; ++kt) {
            const int curA = (kt & 1) << 12;
            const int curB = (kt & 1) << 13;
            if (kt + 1 < DMODEL / 64) {
                const int k0 = (kt + 1) * 64;
#pragma unroll
                for (int c = 0; c < 2; ++c) {
                    int ch = w * 2 + c;
                    async_copy16(AOb + (size_t)(m0 + ch * 8 + srow) * DMODEL + k0 + scol,
                                 sh.o.At + (curA ^ 4096) + ch * 512);
                }
#pragma unroll
                for (int c = 0; c < 4; ++c) {
                    int ch = w * 4 + c;
                    async_copy16(WoT + (size_t)(n0 + ch * 8 + srow) * DMODEL + k0 + scol,
                                 sh.o.Bt + (curB ^ 8192) + ch * 512);
                }
            }
#pragma unroll
            for (int kk = 0; kk < 2; ++kk) {
                short8 af[2], bf[4];
#pragma unroll
                for (int t = 0; t < 2; ++t) {
                    int ra = wm * 32 + t * 16 + l15;
                    af[t] = *(const short8*)(sh.o.At + curA + ra * 64 +
                                             (((kk * 4 + quad) ^ swz) << 3));
                }
#pragma unroll
                for (int t = 0; t < 4; ++t) {
                    int rb = wn * 64 + t * 16 + l15;
                    bf[t] = *(const short8*)(sh.o.Bt + curB + rb * 64 +
                                             (((kk * 4 + quad) ^ swz) << 3));
                }
#pragma unroll
                for (int mt = 0; mt < 2; ++mt)
#pragma unroll
                    for (int nt = 0; nt < 4; ++nt)
                        acc[mt][nt] = __builtin_amdgcn_mfma_f32_16x16x32_bf16(
                            af[mt], bf[nt], acc[mt][nt], 0, 0, 0);
            }
            __syncthreads();
        }

        float bcol[4];
#pragma unroll
        for (int nt = 0; nt < 4; ++nt) bcol[nt] = bo[n0 + wn * 64 + nt * 16 + l15];

#pragma unroll
        for (int mt = 0; mt < 2; ++mt)
#pragma unroll
            for (int reg = 0; reg < 4; ++reg) {
                int row = m0 + wm * 32 + mt * 16 + quad * 4 + reg;
#pragma unroll
                for (int nt = 0; nt < 4; ++nt) {
                    int col = n0 + wn * 64 + nt * 16 + l15;
                    out[(size_t)row * DMODEL + col] = acc[mt][nt][reg] + bcol[nt];
                }
            }
    }
}

// ---------------------------------------------------------------------------
extern "C" void kernel_launch(void* const* d_in, const int* in_sizes, int n_in,
                              void* d_out, int out_size, void* d_ws, size_t ws_size,
                              hipStream_t stream)
{
    const float* x  = (const float*)d_in[0];
    // d_in[1] = causal mask (unused; causality hardcoded)
    const float* Wq = (const float*)d_in[2];
    const float* bq = (const float*)d_in[3];
    const float* Wk = (const float*)d_in[4];
    const float* bk = (const float*)d_in[5];
    const float* Wv = (const float*)d_in[6];
    const float* bv = (const float*)d_in[7];
    const float* Wo = (const float*)d_in[8];
    const float* bo = (const float*)d_in[9];
    float* out = (float*)d_out;

    ushort_t* ws = (ushort_t*)d_ws;
    size_t off = 0;
    ushort_t* xb  = ws + off; off += (size_t)BT * DMODEL;
    ushort_t* WqT = ws + off; off += (size_t)DMODEL * DMODEL;
    ushort_t* WkT = ws + off; off += (size_t)DMODEL * DMODEL;
    ushort_t* WvT = ws + off; off += (size_t)DMODEL * DMODEL;
    ushort_t* WoT = ws + off; off += (size_t)DMODEL * DMODEL;
    ushort_t* Qb  = ws + off; off += (size_t)BT * DMODEL;
    ushort_t* Kb  = ws + off; off += (size_t)BT * DMODEL;
    ushort_t* VTb = ws + off; off += (size_t)BT * DMODEL;
    ushort_t* AOb = ws + off; off += (size_t)BT * DMODEL;
    unsigned* bar = (unsigned*)(ws + off);   // 3 counters, zeroed below

    hipMemsetAsync(bar, 0, 64, stream);
    fused_kernel<<<NBLK, 256, 0, stream>>>(
        x, Wq, bq, Wk, bk, Wv, bv, Wo, bo,
        xb, WqT, WkT, WvT, WoT, Qb, Kb, VTb, AOb, out, bar);
}

// Round 13
// 206.682 us; speedup vs baseline: 2.6589x; 2.6589x over previous
//
#include <hip/hip_runtime.h>
#include <math.h>

typedef unsigned short ushort_t;
typedef short short8 __attribute__((ext_vector_type(8)));
typedef float f32x4 __attribute__((ext_vector_type(4)));

#define DMODEL 1024
#define NHEADS 16
#define DKH    64
#define BATCH  2
#define SEQ    2048
#define BT     (BATCH * SEQ)   // 4096

__device__ __forceinline__ ushort_t f2bf(float f) {
    union { float f; unsigned u; } a; a.f = f;
    return (ushort_t)((a.u + 0x7FFFu + ((a.u >> 16) & 1u)) >> 16);
}

__device__ __forceinline__ void async_copy16(const ushort_t* g, ushort_t* l) {
    __builtin_amdgcn_global_load_lds(
        (__attribute__((address_space(1))) void*)g,
        (__attribute__((address_space(3))) void*)l, 16, 0, 0);
}

// ---------------------------------------------------------------------------
// prep kernel: blocks [0,2048) cast x fp32->bf16; blocks [2048,3072) do the
// weight cast+transpose (W K-major -> WT N-major).
// ---------------------------------------------------------------------------
__global__ __launch_bounds__(256) void prep_kernel(
    const float* __restrict__ x, ushort_t* __restrict__ xb,
    const float* __restrict__ Wq, const float* __restrict__ Wk,
    const float* __restrict__ Wv, const float* __restrict__ Wo,
    ushort_t* __restrict__ WqT, ushort_t* __restrict__ WkT,
    ushort_t* __restrict__ WvT, ushort_t* __restrict__ WoT)
{
    __shared__ ushort_t tile[64][72];
    const int bx = blockIdx.x;
    const int tid = threadIdx.x;

    if (bx < 2048) {
        size_t i = ((size_t)bx * 256 + tid) * 8;
        float4 a = *(const float4*)(x + i);
        float4 b = *(const float4*)(x + i + 4);
        union { ushort_t u[8]; short8 v; } r;
        r.u[0] = f2bf(a.x); r.u[1] = f2bf(a.y); r.u[2] = f2bf(a.z); r.u[3] = f2bf(a.w);
        r.u[4] = f2bf(b.x); r.u[5] = f2bf(b.y); r.u[6] = f2bf(b.z); r.u[7] = f2bf(b.w);
        *(short8*)(xb + i) = r.v;
        return;
    }

    const int idx = bx - 2048;
    const int z  = idx >> 8;
    const int n0 = ((idx >> 4) & 15) * 64;
    const int k0 = (idx & 15) * 64;
    const float* W = (z == 0) ? Wq : (z == 1) ? Wk : (z == 2) ? Wv : Wo;
    ushort_t*   WT = (z == 0) ? WqT : (z == 1) ? WkT : (z == 2) ? WvT : WoT;

    const int r  = tid >> 2;
    const int cb = (tid & 3) * 16;
#pragma unroll
    for (int u = 0; u < 4; ++u) {
        float4 v = *(const float4*)(W + (size_t)(k0 + r) * DMODEL + n0 + cb + u * 4);
        union { ushort_t u4[4]; unsigned long long ll; } p;
        p.u4[0] = f2bf(v.x); p.u4[1] = f2bf(v.y); p.u4[2] = f2bf(v.z); p.u4[3] = f2bf(v.w);
        *(unsigned long long*)&tile[r][cb + u * 4] = p.ll;
    }
    __syncthreads();
    const int n  = tid >> 2;
    const int kb = (tid & 3) * 16;
#pragma unroll
    for (int half = 0; half < 2; ++half) {
        union { ushort_t u8[8]; short8 v; } p;
#pragma unroll
        for (int j = 0; j < 8; ++j) p.u8[j] = tile[kb + half * 8 + j][n];
        *(short8*)(WT + (size_t)(n0 + n) * DMODEL + k0 + kb + half * 8) = p.v;
    }
}

// ---------------------------------------------------------------------------
// QKV GEMM main loop: BM=BN=128, BK=32 dbuf, 32 KB LDS (5 blocks/CU),
// pair-line swizzle (R11-measured best: 55.5 us, 0 conflicts).
// ---------------------------------------------------------------------------
__device__ __forceinline__ void gemm_dbuf_128(
    const ushort_t* __restrict__ A, const ushort_t* __restrict__ B,
    int m0, int n0, ushort_t* At, ushort_t* Bt, f32x4 (&acc)[4][4])
{
    const int tid  = threadIdx.x;
    const int w    = tid >> 6, lane = tid & 63;
    const int l15  = lane & 15, quad = lane >> 4;
    const int wm   = w >> 1, wn = w & 1;
    const int s    = (lane & 7) ^ ((lane >> 3) & 7);
    const int rofs = ((lane >> 3) << 1) | (s >> 2);   // row 0..15 in chunk
    const int cofs = (s & 3) << 3;                    // elem offset in k-slice

    const ushort_t* Asrc = A + (size_t)m0 * DMODEL + cofs;
    const ushort_t* Bsrc = B + (size_t)n0 * DMODEL + cofs;

#pragma unroll
    for (int c = 0; c < 2; ++c) {
        int ch = w * 2 + c;
        async_copy16(Asrc + (size_t)(ch * 16 + rofs) * DMODEL, At + ch * 512);
        async_copy16(Bsrc + (size_t)(ch * 16 + rofs) * DMODEL, Bt + ch * 512);
    }
    __syncthreads();

    for (int kt = 0; kt < DMODEL / 32; ++kt) {
        const int cur = (kt & 1) << 12;          // 4096 ushorts per buffer
        if (kt + 1 < DMODEL / 32) {
            const int nxt = cur ^ 4096;
            const int k0 = (kt + 1) * 32;
#pragma unroll
            for (int c = 0; c < 2; ++c) {
                int ch = w * 2 + c;
                async_copy16(Asrc + (size_t)(ch * 16 + rofs) * DMODEL + k0,
                             At + nxt + ch * 512);
                async_copy16(Bsrc + (size_t)(ch * 16 + rofs) * DMODEL + k0,
                             Bt + nxt + ch * 512);
            }
        }
        short8 af[4], bf[4];
#pragma unroll
        for (int t = 0; t < 4; ++t) {
            int ra = wm * 64 + t * 16 + l15;
            int rb = wn * 64 + t * 16 + l15;
            af[t] = *(const short8*)(At + cur + (ra >> 1) * 64 +
                     (((((ra & 1) << 2) | quad) ^ ((ra >> 1) & 7)) << 3));
            bf[t] = *(const short8*)(Bt + cur + (rb >> 1) * 64 +
                     (((((rb & 1) << 2) | quad) ^ ((rb >> 1) & 7)) << 3));
        }
#pragma unroll
        for (int mt = 0; mt < 4; ++mt)
#pragma unroll
            for (int nt = 0; nt < 4; ++nt)
                acc[mt][nt] = __builtin_amdgcn_mfma_f32_16x16x32_bf16(
                    af[mt], bf[nt], acc[mt][nt], 0, 0, 0);
        __syncthreads();
    }
}

// ---------------------------------------------------------------------------
// out_gemm main loop: BM=64, BN=128, BK=64 dbuf, 48 KB LDS, XOR swizzle
// (R10-measured best for the output projection).
// ---------------------------------------------------------------------------
__device__ __forceinline__ void gemm_dbuf_m64(
    const ushort_t* __restrict__ A, const ushort_t* __restrict__ B,
    int m0, int n0, ushort_t* At, ushort_t* Bt, f32x4 (&acc)[2][4])
{
    const int tid  = threadIdx.x;
    const int w    = tid >> 6, lane = tid & 63;
    const int l15  = lane & 15, quad = lane >> 4;
    const int wm   = w & 1, wn = w >> 1;
    const int srow = lane >> 3;
    const int scol = ((lane & 7) ^ srow) << 3;
    const int swz  = l15 & 7;

#pragma unroll
    for (int c = 0; c < 2; ++c) {
        int ch = w * 2 + c;
        async_copy16(A + (size_t)(m0 + ch * 8 + srow) * DMODEL + scol, At + ch * 512);
    }
#pragma unroll
    for (int c = 0; c < 4; ++c) {
        int ch = w * 4 + c;
        async_copy16(B + (size_t)(n0 + ch * 8 + srow) * DMODEL + scol, Bt + ch * 512);
    }
    __syncthreads();

    for (int kt = 0; kt < DMODEL / 64; ++kt) {
        const int curA = (kt & 1) << 12;         // 4096 ushorts per A buf
        const int curB = (kt & 1) << 13;         // 8192 ushorts per B buf
        if (kt + 1 < DMODEL / 64) {
            const int k0 = (kt + 1) * 64;
#pragma unroll
            for (int c = 0; c < 2; ++c) {
                int ch = w * 2 + c;
                async_copy16(A + (size_t)(m0 + ch * 8 + srow) * DMODEL + k0 + scol,
                             At + (curA ^ 4096) + ch * 512);
            }
#pragma unroll
            for (int c = 0; c < 4; ++c) {
                int ch = w * 4 + c;
                async_copy16(B + (size_t)(n0 + ch * 8 + srow) * DMODEL + k0 + scol,
                             Bt + (curB ^ 8192) + ch * 512);
            }
        }
#pragma unroll
        for (int kk = 0; kk < 2; ++kk) {
            short8 af[2], bf[4];
#pragma unroll
            for (int t = 0; t < 2; ++t) {
                int ra = wm * 32 + t * 16 + l15;
                af[t] = *(const short8*)(At + curA + ra * 64 +
                                         (((kk * 4 + quad) ^ swz) << 3));
            }
#pragma unroll
            for (int t = 0; t < 4; ++t) {
                int rb = wn * 64 + t * 16 + l15;
                bf[t] = *(const short8*)(Bt + curB + rb * 64 +
                                         (((kk * 4 + quad) ^ swz) << 3));
            }
#pragma unroll
            for (int mt = 0; mt < 2; ++mt)
#pragma unroll
                for (int nt = 0; nt < 4; ++nt)
                    acc[mt][nt] = __builtin_amdgcn_mfma_f32_16x16x32_bf16(
                        af[mt], bf[nt], acc[mt][nt], 0, 0, 0);
        }
        __syncthreads();
    }
}

// ---------------------------------------------------------------------------
// QKV projection: xb(4096x1024) @ W + b.
//  z=0,1 (Q,K): bf16 (B,H,T,64).   z=2 (V): bf16 (B,H,64,T') transposed +
//  key-permuted (R7-proven).
// ---------------------------------------------------------------------------
__global__ __launch_bounds__(256) void qkv_gemm(
    const ushort_t* __restrict__ xb,
    const ushort_t* __restrict__ WqT, const ushort_t* __restrict__ WkT,
    const ushort_t* __restrict__ WvT,
    const float* __restrict__ bq, const float* __restrict__ bk,
    const float* __restrict__ bv,
    ushort_t* __restrict__ Qb, ushort_t* __restrict__ Kb, ushort_t* __restrict__ VTo)
{
    const int z = blockIdx.z;
    const ushort_t* WT = (z == 0) ? WqT : (z == 1) ? WkT : WvT;
    const float* bias  = (z == 0) ? bq : (z == 1) ? bk : bv;

    __shared__ ushort_t At[2 * 4096];
    __shared__ ushort_t Bt[2 * 4096];
    const int m0 = blockIdx.x * 128, n0 = blockIdx.y * 128;

    f32x4 zero = {0.f, 0.f, 0.f, 0.f};
    f32x4 acc[4][4];
#pragma unroll
    for (int i = 0; i < 4; ++i)
#pragma unroll
        for (int j = 0; j < 4; ++j) acc[i][j] = zero;

    gemm_dbuf_128(xb, WT, m0, n0, At, Bt, acc);

    const int tid = threadIdx.x, w = tid >> 6, lane = tid & 63;
    const int l15 = lane & 15, quad = lane >> 4;
    const int wm = w >> 1, wn = w & 1;

    float bcol[4];
#pragma unroll
    for (int nt = 0; nt < 4; ++nt) bcol[nt] = bias[n0 + wn * 64 + nt * 16 + l15];

    if (z == 2) {
#pragma unroll
        for (int mt = 0; mt < 4; ++mt) {
            int row0 = m0 + wm * 64 + mt * 16 + quad * 4;
            int b = row0 >> 11, t = row0 & (SEQ - 1);
            int tb = t & ~63;
            int idxp = ((mt & 1) << 2) | (quad << 3) | ((mt >> 1) << 5);
#pragma unroll
            for (int nt = 0; nt < 4; ++nt) {
                int col = n0 + wn * 64 + nt * 16 + l15;
                int h = col >> 6, d = col & 63;
                union { ushort_t u4[4]; unsigned long long ll; } pk;
#pragma unroll
                for (int reg = 0; reg < 4; ++reg)
                    pk.u4[reg] = f2bf(acc[mt][nt][reg] + bcol[nt]);
                *(unsigned long long*)(VTo +
                    ((size_t)(b * NHEADS + h) * DKH + d) * SEQ + tb + idxp) = pk.ll;
            }
        }
    } else {
        ushort_t* out = (z == 0) ? Qb : Kb;
#pragma unroll
        for (int mt = 0; mt < 4; ++mt)
#pragma unroll
            for (int reg = 0; reg < 4; ++reg) {
                int row = m0 + wm * 64 + mt * 16 + quad * 4 + reg;
                int b = row >> 11, t = row & (SEQ - 1);
#pragma unroll
                for (int nt = 0; nt < 4; ++nt) {
                    int col = n0 + wn * 64 + nt * 16 + l15;
                    int h = col >> 6, d = col & 63;
                    out[((((size_t)b * NHEADS + h) * SEQ + t) << 6) + d] =
                        f2bf(acc[mt][nt][reg] + bcol[nt]);
                }
            }
    }
}

// ---------------------------------------------------------------------------
// MFMA flash attention v7 (R10-proven): register P, XCD swizzle,
// v_perm bf16 packing, l via MFMA-with-ones.
// ---------------------------------------------------------------------------
__global__ __launch_bounds__(256) void attn_kernel(
    const ushort_t* __restrict__ Qb, const ushort_t* __restrict__ Kb,
    const ushort_t* __restrict__ VT, ushort_t* __restrict__ AO)
{
    const int bi = blockIdx.x;
    const int bh = bi & 31;                  // same-head blocks share bi%8 (XCD)
    const int b  = bh >> 4, h = bh & 15;
    const int qq = bi >> 5;
    const int tid = threadIdx.x, w = tid >> 6, lane = tid & 63;
    const int l15 = lane & 15, quad = lane >> 4;

    __shared__ ushort_t Kt[2][64 * 64];
    __shared__ ushort_t Vt[2][64 * 64];

    const ushort_t* Kbase = Kb + (((size_t)bh * SEQ) << 6);
    const ushort_t* Vbase = VT + (size_t)bh * DKH * SEQ;

    const int srow = lane >> 3;
    const int schx = (lane & 7) ^ srow;
    const int swz  = l15 & 7;
    const f32x4 zero = {0.f, 0.f, 0.f, 0.f};
    const float cexp = 0.18033688011112042f;   // 0.125 * log2(e)

    union { ushort_t u8[8]; short8 v; } ones;
#pragma unroll
    for (int j = 0; j < 8; ++j) ones.u8[j] = 0x3F80;   // bf16 1.0

    for (int job = 0; job < 2; ++job) {
        const int qt = job ? (31 - qq) : qq;
        const int q0 = qt * 64;
        const int nk = qt + 1;

        short8 qa[2];
#pragma unroll
        for (int ks = 0; ks < 2; ++ks)
            qa[ks] = *(const short8*)(
                Qb + (((size_t)bh * SEQ + q0 + w * 16 + l15) << 6) + ks * 32 + quad * 8);

        f32x4 lacc = zero;
        f32x4 o[4];
#pragma unroll
        for (int dt = 0; dt < 4; ++dt) o[dt] = zero;

#pragma unroll
        for (int c = 0; c < 2; ++c) {
            int chunk = w * 2 + c;
            async_copy16(Kbase + (((size_t)(chunk * 8 + srow)) << 6) + schx * 8,
                         &Kt[0][chunk * 512]);
            async_copy16(Vbase + (size_t)(chunk * 8 + srow) * SEQ + schx * 8,
                         &Vt[0][chunk * 512]);
        }
        __syncthreads();

        for (int kt = 0; kt < nk; ++kt) {
            const int buf = kt & 1;
            if (kt + 1 < nk) {
                const int kt0n = (kt + 1) * 64;
#pragma unroll
                for (int c = 0; c < 2; ++c) {
                    int chunk = w * 2 + c;
                    async_copy16(Kbase + (((size_t)(kt0n + chunk * 8 + srow)) << 6) + schx * 8,
                                 &Kt[buf ^ 1][chunk * 512]);
                    async_copy16(Vbase + (size_t)(chunk * 8 + srow) * SEQ + kt0n + schx * 8,
                                 &Vt[buf ^ 1][chunk * 512]);
                }
            }

            short8 kf[4][2], vf[2][4];
#pragma unroll
            for (int kt_i = 0; kt_i < 4; ++kt_i)
#pragma unroll
                for (int ks = 0; ks < 2; ++ks)
                    kf[kt_i][ks] = *(const short8*)&Kt[buf][(kt_i * 16 + l15) * 64 +
                                                            (((ks * 4 + quad) ^ swz) << 3)];
#pragma unroll
            for (int g = 0; g < 2; ++g)
#pragma unroll
                for (int dt = 0; dt < 4; ++dt)
                    vf[g][dt] = *(const short8*)&Vt[buf][(dt * 16 + l15) * 64 +
                                                         ((((g << 2) | quad) ^ swz) << 3)];

            f32x4 sc[4];
#pragma unroll
            for (int kt_i = 0; kt_i < 4; ++kt_i) sc[kt_i] = zero;
#pragma unroll
            for (int ks = 0; ks < 2; ++ks)
#pragma unroll
                for (int kt_i = 0; kt_i < 4; ++kt_i)
                    sc[kt_i] = __builtin_amdgcn_mfma_f32_16x16x32_bf16(
                        kf[kt_i][ks], qa[ks], sc[kt_i], 0, 0, 0);

            const bool domask = (kt == qt);
            const int qabs = q0 + w * 16 + l15;
            unsigned pka[4], pkb[4];
#pragma unroll
            for (int kt_i = 0; kt_i < 4; ++kt_i) {
                float p[4];
#pragma unroll
                for (int r = 0; r < 4; ++r) {
                    float pv = exp2f(cexp * sc[kt_i][r]);
                    if (domask && (kt * 64 + kt_i * 16 + quad * 4 + r) > qabs) pv = 0.f;
                    p[r] = pv;
                }
                pka[kt_i] = __builtin_amdgcn_perm(
                    __float_as_uint(p[1]), __float_as_uint(p[0]), 0x07060302u);
                pkb[kt_i] = __builtin_amdgcn_perm(
                    __float_as_uint(p[3]), __float_as_uint(p[2]), 0x07060302u);
            }

#pragma unroll
            for (int g = 0; g < 2; ++g) {
                union { unsigned u[4]; short8 v; } pf;
                pf.u[0] = pka[2 * g];
                pf.u[1] = pkb[2 * g];
                pf.u[2] = pka[2 * g + 1];
                pf.u[3] = pkb[2 * g + 1];
                lacc = __builtin_amdgcn_mfma_f32_16x16x32_bf16(
                    pf.v, ones.v, lacc, 0, 0, 0);
#pragma unroll
                for (int dt = 0; dt < 4; ++dt)
                    o[dt] = __builtin_amdgcn_mfma_f32_16x16x32_bf16(
                        pf.v, vf[g][dt], o[dt], 0, 0, 0);
            }

            __syncthreads();
        }

#pragma unroll
        for (int r = 0; r < 4; ++r) {
            float inv = 1.0f / lacc[r];
            int t = q0 + w * 16 + quad * 4 + r;
#pragma unroll
            for (int dt = 0; dt < 4; ++dt)
                AO[((size_t)b * SEQ + t) * DMODEL + h * 64 + dt * 16 + l15] =
                    f2bf(o[dt][r] * inv);
        }
    }
}

// ---------------------------------------------------------------------------
// Output projection: AO(bf16 4096x1024) @ Wo + bo -> fp32 d_out.
// BM=64, BN=128, BK=64 (R10 config).
// ---------------------------------------------------------------------------
__global__ __launch_bounds__(256) void out_gemm(
    const ushort_t* __restrict__ AO, const ushort_t* __restrict__ WoT,
    const float* __restrict__ bo, float* __restrict__ out)
{
    __shared__ ushort_t At[2 * 4096];
    __shared__ ushort_t Bt[2 * 8192];
    const int m0 = blockIdx.x * 64, n0 = blockIdx.y * 128;

    f32x4 zero = {0.f, 0.f, 0.f, 0.f};
    f32x4 acc[2][4];
#pragma unroll
    for (int i = 0; i < 2; ++i)
#pragma unroll
        for (int j = 0; j < 4; ++j) acc[i][j] = zero;

    gemm_dbuf_m64(AO, WoT, m0, n0, At, Bt, acc);

    const int tid = threadIdx.x, w = tid >> 6, lane = tid & 63;
    const int l15 = lane & 15, quad = lane >> 4;
    const int wm = w & 1, wn = w >> 1;

    float bcol[4];
#pragma unroll
    for (int nt = 0; nt < 4; ++nt) bcol[nt] = bo[n0 + wn * 64 + nt * 16 + l15];

#pragma unroll
    for (int mt = 0; mt < 2; ++mt)
#pragma unroll
        for (int reg = 0; reg < 4; ++reg) {
            int row = m0 + wm * 32 + mt * 16 + quad * 4 + reg;
#pragma unroll
            for (int nt = 0; nt < 4; ++nt) {
                int col = n0 + wn * 64 + nt * 16 + l15;
                out[(size_t)row * DMODEL + col] = acc[mt][nt][reg] + bcol[nt];
            }
        }
}

// ---------------------------------------------------------------------------
extern "C" void kernel_launch(void* const* d_in, const int* in_sizes, int n_in,
                              void* d_out, int out_size, void* d_ws, size_t ws_size,
                              hipStream_t stream)
{
    const float* x  = (const float*)d_in[0];
    // d_in[1] = causal mask (unused; causality hardcoded)
    const float* Wq = (const float*)d_in[2];
    const float* bq = (const float*)d_in[3];
    const float* Wk = (const float*)d_in[4];
    const float* bk = (const float*)d_in[5];
    const float* Wv = (const float*)d_in[6];
    const float* bv = (const float*)d_in[7];
    const float* Wo = (const float*)d_in[8];
    const float* bo = (const float*)d_in[9];
    float* out = (float*)d_out;

    ushort_t* ws = (ushort_t*)d_ws;
    size_t off = 0;
    ushort_t* xb  = ws + off; off += (size_t)BT * DMODEL;
    ushort_t* WqT = ws + off; off += (size_t)DMODEL * DMODEL;
    ushort_t* WkT = ws + off; off += (size_t)DMODEL * DMODEL;
    ushort_t* WvT = ws + off; off += (size_t)DMODEL * DMODEL;
    ushort_t* WoT = ws + off; off += (size_t)DMODEL * DMODEL;
    ushort_t* Qb  = ws + off; off += (size_t)BT * DMODEL;
    ushort_t* Kb  = ws + off; off += (size_t)BT * DMODEL;
    ushort_t* VTb = ws + off; off += (size_t)BT * DMODEL;
    ushort_t* AOb = ws + off; off += (size_t)BT * DMODEL;

    prep_kernel<<<2048 + 1024, 256, 0, stream>>>(
        x, xb, Wq, Wk, Wv, Wo, WqT, WkT, WvT, WoT);
    qkv_gemm<<<dim3(BT / 128, DMODEL / 128, 3), 256, 0, stream>>>(
        xb, WqT, WkT, WvT, bq, bk, bv, Qb, Kb, VTb);
    attn_kernel<<<dim3(SEQ / 64 * NHEADS * BATCH / 2), 256, 0, stream>>>(
        Qb, Kb, VTb, AOb);
    out_gemm<<<dim3(BT / 64, DMODEL / 128), 256, 0, stream>>>(
        AOb, WoT, bo, out);
}